// Round 4
// baseline (282.132 us; speedup 1.0000x reference)
//
#include <hip/hip_runtime.h>
#include <hip/hip_bf16.h>

// Problem constants (fixed by the reference)
#define LATENT 32
#define HID 64
#define NB 256          // batch (graphs)
#define NN 200000       // nodes
#define NE 1500000      // edges
#define TWOH 128        // 2*HID

// Output layout (flat floats in d_out)
#define OUT_NODE_OFF   0
#define OUT_EDGE_OFF   (NN * 4)                   // 800000
#define OUT_ENERGY_OFF (OUT_EDGE_OFF + NE * 3)    // 5300000
#define OUT_STRESS_OFF (OUT_ENERGY_OFF + NB * 2)  // 5300512

// Workspace layout (flat floats in d_ws)
#define WS_ZPROJ 0
#define WS_ZC    (WS_ZPROJ + NB*TWOH)
#define WS_P1    (WS_ZC + NB*HID)
#define WS_P2    (WS_P1 + NB*HID)
#define WS_T4    (WS_P2 + NB*HID)
#define WS_W1T   (WS_T4 + NB*NB*4)      // fp16 [128ch][128k]
#define WS_W2T   (WS_W1T + 8192)        // fp16 [64ch][128k]

typedef _Float16 half8 __attribute__((ext_vector_type(8)));
typedef _Float16 half4 __attribute__((ext_vector_type(4)));
typedef float f32x4 __attribute__((ext_vector_type(4)));

#define MT 64                 // nodes per tile
#define NTILES (NN / MT)      // 3125
#define EDGE_BLOCKS ((NE / 4 + 255) / 256)  // 1465
#define SWZ(r) (((r) & 15) << 3)  // element-index XOR swizzle (16B gran)

// ---------------------------------------------------------------------------
// Kernel 1: per-graph precompute (blocks 0..255) + fp16 weight transpose
// (blocks 256..319). 256 threads.
// ---------------------------------------------------------------------------
__global__ void precompute_kernel(
    const float* __restrict__ z,
    const float* __restrict__ lp_w, const float* __restrict__ lp_b,
    const float* __restrict__ nd1_w,
    const float* __restrict__ ed1_w,
    const float* __restrict__ en1_w, const float* __restrict__ en1_b,
    const float* __restrict__ en2_w, const float* __restrict__ en2_b,
    const float* __restrict__ st1_w, const float* __restrict__ st1_b,
    const float* __restrict__ st2_w, const float* __restrict__ st2_b,
    const float* __restrict__ nep_w,
    float* __restrict__ z_proj, float* __restrict__ zc,
    float* __restrict__ P1, float* __restrict__ P2,
    _Float16* __restrict__ w1T, _Float16* __restrict__ w2T,
    float* __restrict__ out_energy, float* __restrict__ out_stress)
{
    const int t = threadIdx.x;

    if (blockIdx.x >= NB) {
        const int i = (blockIdx.x - NB) * 256 + t;
        if (i < TWOH * TWOH) {
            const int n = i >> 7, k = i & 127;
            w1T[i] = (_Float16)nep_w[k * TWOH + n];
        }
        if (i < HID * TWOH) {
            const int n = i >> 7, k = i & 127;
            w2T[i] = (_Float16)nd1_w[k * HID + n];
        }
        return;
    }

    const int b = blockIdx.x;
    __shared__ float zrow[LATENT];
    __shared__ float zp[TWOH];
    __shared__ float h_en[HID];
    __shared__ float h_st[HID];

    if (t < LATENT) zrow[t] = z[b * LATENT + t];
    __syncthreads();

    if (t < TWOH) {
        float a = lp_b[t];
        #pragma unroll
        for (int k = 0; k < LATENT; ++k)
            a = fmaf(zrow[k], lp_w[k * TWOH + t], a);
        a = fmaxf(a, 0.f);
        zp[t] = a;
        z_proj[b * TWOH + t] = a;
    }
    if (t < HID) {
        float ae = en1_b[t];
        float as = st1_b[t];
        #pragma unroll
        for (int k = 0; k < LATENT; ++k) {
            ae = fmaf(zrow[k], en1_w[k * HID + t], ae);
            as = fmaf(zrow[k], st1_w[k * HID + t], as);
        }
        h_en[t] = fmaxf(ae, 0.f);
        h_st[t] = fmaxf(as, 0.f);
    }
    __syncthreads();

    if (t < HID) {
        float a = 0.f, p1 = 0.f, p2 = 0.f;
        #pragma unroll 8
        for (int k = 0; k < TWOH; ++k) {
            const float zk = zp[k];
            a  = fmaf(zk, nd1_w[k * HID + t], a);
            p1 = fmaf(zk, ed1_w[k * HID + t], p1);
            p2 = fmaf(zk, ed1_w[(TWOH + k) * HID + t], p2);
        }
        zc[b * HID + t] = a;
        P1[b * HID + t] = p1;
        P2[b * HID + t] = p2;
    }
    if (t < 2) {
        float a = en2_b[t];
        #pragma unroll 8
        for (int k = 0; k < HID; ++k) a = fmaf(h_en[k], en2_w[k * 2 + t], a);
        out_energy[b * 2 + t] = a;
    }
    if (t >= 16 && t < 25) {
        const int j = t - 16;
        float a = st2_b[j];
        #pragma unroll 8
        for (int k = 0; k < HID; ++k) a = fmaf(h_st[k], st2_w[k * 9 + j], a);
        out_stress[b * 9 + j] = a;
    }
}

// ---------------------------------------------------------------------------
// Kernel 2: edge pair table. grid=256 (gs), block=256 (gd). float4 P2 loads.
// ---------------------------------------------------------------------------
__global__ void edge_table_kernel(
    const float* __restrict__ P1, const float* __restrict__ P2,
    const float* __restrict__ ed1_b,
    const float* __restrict__ ed2_w, const float* __restrict__ ed2_b,
    float4* __restrict__ T4)
{
    const int gs = blockIdx.x;
    const int t  = threadIdx.x;

    __shared__ float p1s[HID];   // P1[gs] + ed1_b, pre-summed
    __shared__ float w2s[HID * 3];
    __shared__ float b2s[3];

    if (t < HID) p1s[t] = P1[gs * HID + t] + ed1_b[t];
    if (t >= 64 && t < 64 + HID * 3) w2s[t - 64] = ed2_w[t - 64];
    if (t < 3) b2s[t] = ed2_b[t];
    __syncthreads();

    float o0 = b2s[0], o1 = b2s[1], o2 = b2s[2];
    const f32x4* __restrict__ p2 = reinterpret_cast<const f32x4*>(&P2[t * HID]);
    #pragma unroll 4
    for (int k4 = 0; k4 < 16; ++k4) {
        const f32x4 pv = p2[k4];
        #pragma unroll
        for (int j = 0; j < 4; ++j) {
            const int k = k4 * 4 + j;
            const float h = fmaxf(p1s[k] + pv[j], 0.f);
            o0 = fmaf(h, w2s[k * 3 + 0], o0);
            o1 = fmaf(h, w2s[k * 3 + 1], o1);
            o2 = fmaf(h, w2s[k * 3 + 2], o2);
        }
    }
    T4[gs * NB + t] = make_float4(o0, o1, o2, 0.f);
}

// ---------------------------------------------------------------------------
// Kernel 3: fused node + edge, ONE-SHOT blocks (max TLP).
//  Blocks [0, NTILES): one 64-node tile each.
//    Swapped-operand MFMA; emb B-frags loaded DIRECTLY from global (each lane
//    needs 8 contiguous fp32 -> 2x float4 + cvt). No emb LDS, no staging
//    barrier. LDS only for the cross-wave nep exchange + stage-3 partials
//    (20.8 KB -> up to 7 blocks/CU by LDS).
//  Blocks [NTILES, +EDGE_BLOCKS): 1024-edge gather chunks from pair table.
//  Scheduler interleaves node (MFMA/stream) and edge (gather) blocks per CU.
// ---------------------------------------------------------------------------
__global__ __launch_bounds__(256, 3)
void node_edge_kernel(
    const float* __restrict__ node_emb,
    const int*   __restrict__ graph_id,
    const _Float16* __restrict__ w1T,
    const float* __restrict__ nep_b,
    const _Float16* __restrict__ w2T,
    const float* __restrict__ nd1_b,
    const float* __restrict__ nd2_w, const float* __restrict__ nd2_b,
    const float* __restrict__ zc,
    const int* __restrict__ src, const int* __restrict__ dst,
    const float4* __restrict__ T4,
    float* __restrict__ out_node, float* __restrict__ out_edge)
{
    const int tid = threadIdx.x;
    const int bid = blockIdx.x;

    if (bid >= NTILES) {
        // ---------------- edge path ----------------
        const int e0 = ((bid - NTILES) * 256 + tid) * 4;
        if (e0 >= NE) return;
        const int4 s4 = *reinterpret_cast<const int4*>(&src[e0]);
        const int4 d4 = *reinterpret_cast<const int4*>(&dst[e0]);
        const int ss[4] = {s4.x, s4.y, s4.z, s4.w};
        const int dd[4] = {d4.x, d4.y, d4.z, d4.w};
        float o[12];
        #pragma unroll
        for (int j = 0; j < 4; ++j) {
            const int gs = graph_id[ss[j]];
            const int gd = graph_id[dd[j]];
            const float4 tv = T4[gs * NB + gd];
            o[j * 3 + 0] = tv.x; o[j * 3 + 1] = tv.y; o[j * 3 + 2] = tv.z;
        }
        float4* outp = reinterpret_cast<float4*>(&out_edge[(size_t)e0 * 3]);
        outp[0] = make_float4(o[0], o[1], o[2],  o[3]);
        outp[1] = make_float4(o[4], o[5], o[6],  o[7]);
        outp[2] = make_float4(o[8], o[9], o[10], o[11]);
        return;
    }

    // ---------------- node path (one tile) ----------------
    __shared__ _Float16 nepL[MT * TWOH];    // 16 KB, swizzled [node][ch]
    __shared__ float    partL[4 * MT * 4];  // 4 KB: [wave][node][o]
    __shared__ int      gidL[MT];

    const int wv   = tid >> 6;
    const int lane = tid & 63;
    const int lrow = lane & 15;
    const int kg   = lane >> 4;
    const size_t nbase = (size_t)bid * MT;

    if (tid < MT) gidL[tid] = graph_id[nbase + tid];

    // weight fragments (L2-resident; 192 B/thread)
    half8 w1A[2][4];   // stage1 A: channels wv*32+cht*16+lrow, k=kb*32+kg*8
    #pragma unroll
    for (int cht = 0; cht < 2; ++cht)
        #pragma unroll
        for (int kb = 0; kb < 4; ++kb)
            w1A[cht][kb] = *reinterpret_cast<const half8*>(
                &w1T[(wv * 32 + cht * 16 + lrow) * TWOH + kb * 32 + kg * 8]);
    half8 w2A[4];      // stage2 A: channels wv*16+lrow
    #pragma unroll
    for (int kb = 0; kb < 4; ++kb)
        w2A[kb] = *reinterpret_cast<const half8*>(
            &w2T[(wv * 16 + lrow) * TWOH + kb * 32 + kg * 8]);

    f32x4 b1r[2], b2r, w3r[4];
    #pragma unroll
    for (int cht = 0; cht < 2; ++cht)
        b1r[cht] = *reinterpret_cast<const f32x4*>(&nep_b[wv * 32 + cht * 16 + kg * 4]);
    b2r = *reinterpret_cast<const f32x4*>(&nd1_b[wv * 16 + kg * 4]);
    #pragma unroll
    for (int j = 0; j < 4; ++j)
        w3r[j] = *reinterpret_cast<const f32x4*>(&nd2_w[(wv * 16 + kg * 4 + j) * 4]);
    const float b3 = nd2_b[tid & 3];

    // ---- Stage 1: nep^T = relu(W1^T @ emb^T + b1); emb B-frags direct ----
    f32x4 acc1[2][4];
    #pragma unroll
    for (int cht = 0; cht < 2; ++cht)
        #pragma unroll
        for (int nt = 0; nt < 4; ++nt)
            acc1[cht][nt] = (f32x4){0.f, 0.f, 0.f, 0.f};

    #pragma unroll
    for (int nt = 0; nt < 4; ++nt) {
        // lane reads node (nt*16+lrow), cols kb*32+kg*8 .. +8 (two float4)
        const float* ep = node_emb + (nbase + nt * 16 + lrow) * TWOH + kg * 8;
        f32x4 u[4], v[4];
        #pragma unroll
        for (int kb = 0; kb < 4; ++kb) {
            u[kb] = *reinterpret_cast<const f32x4*>(ep + kb * 32);
            v[kb] = *reinterpret_cast<const f32x4*>(ep + kb * 32 + 4);
        }
        #pragma unroll
        for (int kb = 0; kb < 4; ++kb) {
            half8 h;
            h[0] = (_Float16)u[kb][0]; h[1] = (_Float16)u[kb][1];
            h[2] = (_Float16)u[kb][2]; h[3] = (_Float16)u[kb][3];
            h[4] = (_Float16)v[kb][0]; h[5] = (_Float16)v[kb][1];
            h[6] = (_Float16)v[kb][2]; h[7] = (_Float16)v[kb][3];
            acc1[0][nt] = __builtin_amdgcn_mfma_f32_16x16x32_f16(
                w1A[0][kb], h, acc1[0][nt], 0, 0, 0);
            acc1[1][nt] = __builtin_amdgcn_mfma_f32_16x16x32_f16(
                w1A[1][kb], h, acc1[1][nt], 0, 0, 0);
        }
    }
    // epilogue: bias+relu -> fp16 -> packed half4 writes (contiguous channels)
    #pragma unroll
    for (int cht = 0; cht < 2; ++cht)
        #pragma unroll
        for (int nt = 0; nt < 4; ++nt) {
            const int node = nt * 16 + lrow;
            const int ch = wv * 32 + cht * 16 + kg * 4;
            half4 h;
            #pragma unroll
            for (int j = 0; j < 4; ++j)
                h[j] = (_Float16)fmaxf(acc1[cht][nt][j] + b1r[cht][j], 0.f);
            *reinterpret_cast<half4*>(&nepL[(node * TWOH + ch) ^ SWZ(node)]) = h;
        }
    __syncthreads();   // B1: nep ready

    // ---- Stage 2: tt^T = relu(W2^T @ nep^T + b2 + zc[g]) + stage-3 partials ----
    f32x4 acc2[4];
    #pragma unroll
    for (int nt = 0; nt < 4; ++nt) acc2[nt] = (f32x4){0.f, 0.f, 0.f, 0.f};

    #pragma unroll
    for (int nt = 0; nt < 4; ++nt) {
        #pragma unroll
        for (int kb = 0; kb < 4; ++kb) {
            const int node = nt * 16 + lrow;
            const int e = node * TWOH + kb * 32 + kg * 8;
            const half8 nB = *reinterpret_cast<const half8*>(&nepL[e ^ SWZ(node)]);
            acc2[nt] = __builtin_amdgcn_mfma_f32_16x16x32_f16(
                w2A[kb], nB, acc2[nt], 0, 0, 0);
        }
    }

    f32x4 p[4];
    #pragma unroll
    for (int nt = 0; nt < 4; ++nt) {
        const int node = nt * 16 + lrow;
        const int g = gidL[node];
        const f32x4 z4 = *reinterpret_cast<const f32x4*>(
            &zc[(size_t)g * HID + wv * 16 + kg * 4]);
        f32x4 t4;
        #pragma unroll
        for (int j = 0; j < 4; ++j)
            t4[j] = fmaxf(acc2[nt][j] + b2r[j] + z4[j], 0.f);
        f32x4 pp = t4[0] * w3r[0];
        pp += t4[1] * w3r[1];
        pp += t4[2] * w3r[2];
        pp += t4[3] * w3r[3];
        p[nt] = pp;
    }
    #pragma unroll
    for (int nt = 0; nt < 4; ++nt) {
        #pragma unroll
        for (int j = 0; j < 4; ++j) {
            p[nt][j] += __shfl_xor(p[nt][j], 16, 64);
            p[nt][j] += __shfl_xor(p[nt][j], 32, 64);
        }
    }
    if (lane < 16) {
        #pragma unroll
        for (int nt = 0; nt < 4; ++nt)
            *reinterpret_cast<f32x4*>(
                &partL[(wv * MT + nt * 16 + lrow) * 4]) = p[nt];
    }
    __syncthreads();   // B2: partials ready

    // ---- final cross-wave sum + coalesced store ----
    {
        const int node = tid >> 2;
        const int o    = tid & 3;
        const int ix = node * 4 + o;
        const float s = partL[ix] + partL[256 + ix] +
                        partL[512 + ix] + partL[768 + ix] + b3;
        out_node[(nbase + node) * 4 + o] = s;
    }
}

// ---------------------------------------------------------------------------
extern "C" void kernel_launch(void* const* d_in, const int* in_sizes, int n_in,
                              void* d_out, int out_size, void* d_ws, size_t ws_size,
                              hipStream_t stream)
{
    const float* z        = (const float*)d_in[0];
    const float* node_emb = (const float*)d_in[1];
    const int*   graph_id = (const int*)  d_in[2];
    const int*   src      = (const int*)  d_in[3];
    const int*   dst      = (const int*)  d_in[4];
    const float* lp_w  = (const float*)d_in[5];
    const float* lp_b  = (const float*)d_in[6];
    const float* nep_w = (const float*)d_in[7];
    const float* nep_b = (const float*)d_in[8];
    const float* nd1_w = (const float*)d_in[9];
    const float* nd1_b = (const float*)d_in[10];
    const float* nd2_w = (const float*)d_in[11];
    const float* nd2_b = (const float*)d_in[12];
    const float* ed1_w = (const float*)d_in[13];
    const float* ed1_b = (const float*)d_in[14];
    const float* ed2_w = (const float*)d_in[15];
    const float* ed2_b = (const float*)d_in[16];
    const float* en1_w = (const float*)d_in[17];
    const float* en1_b = (const float*)d_in[18];
    const float* en2_w = (const float*)d_in[19];
    const float* en2_b = (const float*)d_in[20];
    const float* st1_w = (const float*)d_in[21];
    const float* st1_b = (const float*)d_in[22];
    const float* st2_w = (const float*)d_in[23];
    const float* st2_b = (const float*)d_in[24];

    float* out = (float*)d_out;
    float* out_node   = out + OUT_NODE_OFF;
    float* out_edge   = out + OUT_EDGE_OFF;
    float* out_energy = out + OUT_ENERGY_OFF;
    float* out_stress = out + OUT_STRESS_OFF;

    float* ws     = (float*)d_ws;
    float* z_proj = ws + WS_ZPROJ;
    float* zc     = ws + WS_ZC;
    float* P1     = ws + WS_P1;
    float* P2     = ws + WS_P2;
    float4* T4    = (float4*)(ws + WS_T4);
    _Float16* w1T = (_Float16*)(ws + WS_W1T);
    _Float16* w2T = (_Float16*)(ws + WS_W2T);

    precompute_kernel<<<NB + 64, 256, 0, stream>>>(
        z, lp_w, lp_b, nd1_w, ed1_w,
        en1_w, en1_b, en2_w, en2_b, st1_w, st1_b, st2_w, st2_b, nep_w,
        z_proj, zc, P1, P2, w1T, w2T, out_energy, out_stress);

    edge_table_kernel<<<NB, NB, 0, stream>>>(P1, P2, ed1_b, ed2_w, ed2_b, T4);

    node_edge_kernel<<<NTILES + EDGE_BLOCKS, 256, 0, stream>>>(
        node_emb, graph_id, w1T, nep_b, w2T, nd1_b, nd2_w, nd2_b, zc,
        src, dst, T4, out_node, out_edge);
}

// Round 5
// 255.042 us; speedup vs baseline: 1.1062x; 1.1062x over previous
//
#include <hip/hip_runtime.h>
#include <hip/hip_bf16.h>

// Problem constants (fixed by the reference)
#define LATENT 32
#define HID 64
#define NB 256          // batch (graphs)
#define NN 200000       // nodes
#define NE 1500000      // edges
#define TWOH 128        // 2*HID

// Output layout (flat floats in d_out)
#define OUT_NODE_OFF   0
#define OUT_EDGE_OFF   (NN * 4)                   // 800000
#define OUT_ENERGY_OFF (OUT_EDGE_OFF + NE * 3)    // 5300000
#define OUT_STRESS_OFF (OUT_ENERGY_OFF + NB * 2)  // 5300512

// Workspace layout (flat floats in d_ws)
#define WS_ZPROJ 0
#define WS_ZC    (WS_ZPROJ + NB*TWOH)
#define WS_P1    (WS_ZC + NB*HID)
#define WS_P2    (WS_P1 + NB*HID)
#define WS_T4    (WS_P2 + NB*HID)
#define WS_W1T   (WS_T4 + NB*NB*4)      // fp16 [128ch][128k], k-slot swizzled
#define WS_W2T   (WS_W1T + 8192)        // fp16 [64ch][128k],  k-slot swizzled

typedef _Float16 half8 __attribute__((ext_vector_type(8)));
typedef _Float16 half4 __attribute__((ext_vector_type(4)));
typedef float f32x4 __attribute__((ext_vector_type(4)));
typedef int i32x2 __attribute__((ext_vector_type(2)));
typedef int i32x4 __attribute__((ext_vector_type(4)));

#define WTILES 12500            // 16-node wave tiles
#define TPW 2                   // tiles per wave
#define NODE_BLK 782            // 782*8 waves * 2 tiles = 12512 >= 12500
#define EDGE_BLK 733            // 733*512 threads * 4 edges = 1501184 >= NE

// ---------------------------------------------------------------------------
// Kernel 1: per-graph precompute (blocks 0..255) + swizzled fp16 weight
// transpose (blocks 256..319). 256 threads.
// w1s[ch][slot^ (ch&7)][0..7] = nep_w[k][ch]  (slot = k>>3), same for w2s.
// ---------------------------------------------------------------------------
__global__ void precompute_kernel(
    const float* __restrict__ z,
    const float* __restrict__ lp_w, const float* __restrict__ lp_b,
    const float* __restrict__ nd1_w,
    const float* __restrict__ ed1_w,
    const float* __restrict__ en1_w, const float* __restrict__ en1_b,
    const float* __restrict__ en2_w, const float* __restrict__ en2_b,
    const float* __restrict__ st1_w, const float* __restrict__ st1_b,
    const float* __restrict__ st2_w, const float* __restrict__ st2_b,
    const float* __restrict__ nep_w,
    float* __restrict__ z_proj, float* __restrict__ zc,
    float* __restrict__ P1, float* __restrict__ P2,
    _Float16* __restrict__ w1s, _Float16* __restrict__ w2s,
    float* __restrict__ out_energy, float* __restrict__ out_stress)
{
    const int t = threadIdx.x;

    if (blockIdx.x >= NB) {
        const int i = (blockIdx.x - NB) * 256 + t;
        if (i < TWOH * TWOH) {
            const int ch = i >> 7, k = i & 127;
            const int dst = ch * TWOH + (((k >> 3) ^ (ch & 7)) << 3) + (k & 7);
            w1s[dst] = (_Float16)nep_w[k * TWOH + ch];
        }
        if (i < HID * TWOH) {
            const int ch = i >> 7, k = i & 127;
            const int dst = ch * TWOH + (((k >> 3) ^ (ch & 7)) << 3) + (k & 7);
            w2s[dst] = (_Float16)nd1_w[k * HID + ch];
        }
        return;
    }

    const int b = blockIdx.x;
    __shared__ float zrow[LATENT];
    __shared__ float zp[TWOH];
    __shared__ float h_en[HID];
    __shared__ float h_st[HID];

    if (t < LATENT) zrow[t] = z[b * LATENT + t];
    __syncthreads();

    if (t < TWOH) {
        float a = lp_b[t];
        #pragma unroll
        for (int k = 0; k < LATENT; ++k)
            a = fmaf(zrow[k], lp_w[k * TWOH + t], a);
        a = fmaxf(a, 0.f);
        zp[t] = a;
        z_proj[b * TWOH + t] = a;
    }
    if (t < HID) {
        float ae = en1_b[t];
        float as = st1_b[t];
        #pragma unroll
        for (int k = 0; k < LATENT; ++k) {
            ae = fmaf(zrow[k], en1_w[k * HID + t], ae);
            as = fmaf(zrow[k], st1_w[k * HID + t], as);
        }
        h_en[t] = fmaxf(ae, 0.f);
        h_st[t] = fmaxf(as, 0.f);
    }
    __syncthreads();

    if (t < HID) {
        float a = 0.f, p1 = 0.f, p2 = 0.f;
        #pragma unroll 8
        for (int k = 0; k < TWOH; ++k) {
            const float zk = zp[k];
            a  = fmaf(zk, nd1_w[k * HID + t], a);
            p1 = fmaf(zk, ed1_w[k * HID + t], p1);
            p2 = fmaf(zk, ed1_w[(TWOH + k) * HID + t], p2);
        }
        zc[b * HID + t] = a;
        P1[b * HID + t] = p1;
        P2[b * HID + t] = p2;
    }
    if (t < 2) {
        float a = en2_b[t];
        #pragma unroll 8
        for (int k = 0; k < HID; ++k) a = fmaf(h_en[k], en2_w[k * 2 + t], a);
        out_energy[b * 2 + t] = a;
    }
    if (t >= 16 && t < 25) {
        const int j = t - 16;
        float a = st2_b[j];
        #pragma unroll 8
        for (int k = 0; k < HID; ++k) a = fmaf(h_st[k], st2_w[k * 9 + j], a);
        out_stress[b * 9 + j] = a;
    }
}

// ---------------------------------------------------------------------------
// Kernel 2: edge pair table. grid=256 (gs), block=256 (gd).
// ---------------------------------------------------------------------------
__global__ void edge_table_kernel(
    const float* __restrict__ P1, const float* __restrict__ P2,
    const float* __restrict__ ed1_b,
    const float* __restrict__ ed2_w, const float* __restrict__ ed2_b,
    float4* __restrict__ T4)
{
    const int gs = blockIdx.x;
    const int t  = threadIdx.x;

    __shared__ float p1s[HID];
    __shared__ float w2s_[HID * 3];
    __shared__ float b2s[3];

    if (t < HID) p1s[t] = P1[gs * HID + t] + ed1_b[t];
    if (t >= 64 && t < 64 + HID * 3) w2s_[t - 64] = ed2_w[t - 64];
    if (t < 3) b2s[t] = ed2_b[t];
    __syncthreads();

    float o0 = b2s[0], o1 = b2s[1], o2 = b2s[2];
    const f32x4* __restrict__ p2 = reinterpret_cast<const f32x4*>(&P2[t * HID]);
    #pragma unroll 4
    for (int k4 = 0; k4 < 16; ++k4) {
        const f32x4 pv = p2[k4];
        #pragma unroll
        for (int j = 0; j < 4; ++j) {
            const int k = k4 * 4 + j;
            const float h = fmaxf(p1s[k] + pv[j], 0.f);
            o0 = fmaf(h, w2s_[k * 3 + 0], o0);
            o1 = fmaf(h, w2s_[k * 3 + 1], o1);
            o2 = fmaf(h, w2s_[k * 3 + 2], o2);
        }
    }
    T4[gs * NB + t] = make_float4(o0, o1, o2, 0.f);
}

// ---------------------------------------------------------------------------
// Kernel 3: fused node + edge. INDEPENDENT-WAVE node path.
//  Node blocks: 512 thr, stage 50 KB weights -> LDS (one barrier), then each
//  wave owns 16-node tiles end-to-end: emb B-frags direct from global (read
//  once), nep in-register (32 ds_bpermute exchange), stage-3 via shfl_xor.
//  Zero per-tile barriers -> 16 independent waves/CU hide all latency.
//  Edge blocks: pure gather from pair table (skip LDS, return early).
// ---------------------------------------------------------------------------
__global__ __launch_bounds__(512, 4)
void node_edge_kernel(
    const float* __restrict__ node_emb,
    const int*   __restrict__ graph_id,
    const _Float16* __restrict__ w1s,
    const float* __restrict__ nep_b,
    const _Float16* __restrict__ w2s,
    const float* __restrict__ nd1_b,
    const float* __restrict__ nd2_w, const float* __restrict__ nd2_b,
    const float* __restrict__ zc,
    const int* __restrict__ src, const int* __restrict__ dst,
    const float4* __restrict__ T4,
    float* __restrict__ out_node, float* __restrict__ out_edge)
{
    const int tid = threadIdx.x;
    const int bid = blockIdx.x;

    if (bid >= NODE_BLK) {
        // ---------------- edge path ----------------
        const int e0 = ((bid - NODE_BLK) * 512 + tid) * 4;
        if (e0 >= NE) return;
        const int4 s4 = *reinterpret_cast<const int4*>(&src[e0]);
        const int4 d4 = *reinterpret_cast<const int4*>(&dst[e0]);
        const int ss[4] = {s4.x, s4.y, s4.z, s4.w};
        const int dd[4] = {d4.x, d4.y, d4.z, d4.w};
        float o[12];
        #pragma unroll
        for (int j = 0; j < 4; ++j) {
            const int gs = graph_id[ss[j]];
            const int gd = graph_id[dd[j]];
            const float4 tv = T4[gs * NB + gd];
            o[j * 3 + 0] = tv.x; o[j * 3 + 1] = tv.y; o[j * 3 + 2] = tv.z;
        }
        float4* outp = reinterpret_cast<float4*>(&out_edge[(size_t)e0 * 3]);
        outp[0] = make_float4(o[0], o[1], o[2],  o[3]);
        outp[1] = make_float4(o[4], o[5], o[6],  o[7]);
        outp[2] = make_float4(o[8], o[9], o[10], o[11]);
        return;
    }

    // ---------------- node path ----------------
    __shared__ _Float16 w1L[TWOH * TWOH];  // 32 KB
    __shared__ _Float16 w2L[HID * TWOH];   // 16 KB
    __shared__ float    b1L[TWOH];         // 512 B
    __shared__ float    b2L[HID];          // 256 B
    __shared__ float    w3L[HID * 4];      // 1 KB

    // ---- stage weights into LDS (the only barrier) ----
    {
        const uint4* g1 = reinterpret_cast<const uint4*>(w1s);
        uint4* l1 = reinterpret_cast<uint4*>(w1L);
        #pragma unroll
        for (int i = 0; i < 4; ++i) l1[tid + 512 * i] = g1[tid + 512 * i];
        const uint4* g2 = reinterpret_cast<const uint4*>(w2s);
        uint4* l2 = reinterpret_cast<uint4*>(w2L);
        #pragma unroll
        for (int i = 0; i < 2; ++i) l2[tid + 512 * i] = g2[tid + 512 * i];
        if (tid < TWOH)    b1L[tid] = nep_b[tid];
        if (tid < HID)     b2L[tid] = nd1_b[tid];
        if (tid < HID * 4) w3L[tid] = nd2_w[tid];
    }
    __syncthreads();

    const int wv   = tid >> 6;
    const int lane = tid & 63;
    const int lrow = lane & 15;     // node within tile / ch row within tile
    const int kg   = lane >> 4;     // k-group
    const int hi   = kg >> 1;       // selects vv[2kb+hi] in the exchange
    const int srcA = lrow | ((kg & 1) << 5);
    const int srcB = srcA | 16;

    #pragma unroll
    for (int tt = 0; tt < TPW; ++tt) {
        const int tile = (bid * 8 + wv) * TPW + tt;
        if (tile >= WTILES) break;
        const size_t nb16 = (size_t)tile * 16;
        const int node = (int)nb16 + lrow;

        // graph id + zc gather (issued early; consumed in stage 2 init)
        const int g = graph_id[node];
        f32x4 zv[4];
        #pragma unroll
        for (int c2 = 0; c2 < 4; ++c2)
            zv[c2] = *reinterpret_cast<const f32x4*>(
                &zc[(size_t)g * HID + c2 * 16 + kg * 4]);

        // ---- stage 1: nep^T = relu(W1^T @ emb^T + b1) ----
        f32x4 acc1[8];
        #pragma unroll
        for (int cht = 0; cht < 8; ++cht)
            acc1[cht] = *reinterpret_cast<const f32x4*>(&b1L[cht * 16 + kg * 4]);

        #pragma unroll
        for (int kb = 0; kb < 4; ++kb) {
            const float* ep = node_emb + (size_t)node * TWOH + kb * 32 + kg * 8;
            const f32x4 u = *reinterpret_cast<const f32x4*>(ep);
            const f32x4 v = *reinterpret_cast<const f32x4*>(ep + 4);
            half8 h;
            h[0] = (_Float16)u[0]; h[1] = (_Float16)u[1];
            h[2] = (_Float16)u[2]; h[3] = (_Float16)u[3];
            h[4] = (_Float16)v[0]; h[5] = (_Float16)v[1];
            h[6] = (_Float16)v[2]; h[7] = (_Float16)v[3];
            const int koff = (((kb * 4 + kg) ^ (lrow & 7)) << 3);
            #pragma unroll
            for (int cht = 0; cht < 8; ++cht) {
                const half8 w = *reinterpret_cast<const half8*>(
                    &w1L[(cht * 16 + lrow) * TWOH + koff]);
                acc1[cht] = __builtin_amdgcn_mfma_f32_16x16x32_f16(
                    w, h, acc1[cht], 0, 0, 0);
            }
        }

        // relu -> fp16, keep in registers (lane: node=lrow, ch=cht*16+kg*4+r)
        half4 vv[8];
        #pragma unroll
        for (int cht = 0; cht < 8; ++cht) {
            half4 hv;
            #pragma unroll
            for (int j = 0; j < 4; ++j)
                hv[j] = (_Float16)fmaxf(acc1[cht][j], 0.f);
            vv[cht] = hv;
        }

        // ---- stage 2: tt^T = relu(W2^T @ nep^T + b2 + zc[g]) ----
        f32x4 acc2[4];
        #pragma unroll
        for (int c2 = 0; c2 < 4; ++c2)
            acc2[c2] = *reinterpret_cast<const f32x4*>(&b2L[c2 * 16 + kg * 4])
                       + zv[c2];

        #pragma unroll
        for (int kb = 0; kb < 4; ++kb) {
            // lane exchange: build B-frag (node=lrow, ch=kb*32+kg*8..+8)
            const i32x2 a0 = __builtin_bit_cast(i32x2, vv[2 * kb]);
            const i32x2 a1 = __builtin_bit_cast(i32x2, vv[2 * kb + 1]);
            const int A0x = __shfl(a0.x, srcA, 64), A0y = __shfl(a0.y, srcA, 64);
            const int A1x = __shfl(a1.x, srcA, 64), A1y = __shfl(a1.y, srcA, 64);
            const int B0x = __shfl(a0.x, srcB, 64), B0y = __shfl(a0.y, srcB, 64);
            const int B1x = __shfl(a1.x, srcB, 64), B1y = __shfl(a1.y, srcB, 64);
            i32x4 wp;
            wp.x = hi ? A1x : A0x;  wp.y = hi ? A1y : A0y;
            wp.z = hi ? B1x : B0x;  wp.w = hi ? B1y : B0y;
            const half8 nB = __builtin_bit_cast(half8, wp);

            const int koff = (((kb * 4 + kg) ^ (lrow & 7)) << 3);
            #pragma unroll
            for (int c2 = 0; c2 < 4; ++c2) {
                const half8 w = *reinterpret_cast<const half8*>(
                    &w2L[(c2 * 16 + lrow) * TWOH + koff]);
                acc2[c2] = __builtin_amdgcn_mfma_f32_16x16x32_f16(
                    w, nB, acc2[c2], 0, 0, 0);
            }
        }

        // ---- stage 3: out = tt @ w3 + b3, shfl reduce over kg groups ----
        f32x4 p = {0.f, 0.f, 0.f, 0.f};
        #pragma unroll
        for (int c2 = 0; c2 < 4; ++c2) {
            #pragma unroll
            for (int r = 0; r < 4; ++r) {
                const float tval = fmaxf(acc2[c2][r], 0.f);
                const f32x4 w3v = *reinterpret_cast<const f32x4*>(
                    &w3L[(c2 * 16 + kg * 4 + r) * 4]);
                p += tval * w3v;
            }
        }
        #pragma unroll
        for (int j = 0; j < 4; ++j) {
            p[j] += __shfl_xor(p[j], 16, 64);
            p[j] += __shfl_xor(p[j], 32, 64);
        }
        if (kg == 0) {
            const f32x4 b3 = *reinterpret_cast<const f32x4*>(&nd2_b[0]);
            *reinterpret_cast<f32x4*>(&out_node[(size_t)node * 4]) = p + b3;
        }
    }
}

// ---------------------------------------------------------------------------
extern "C" void kernel_launch(void* const* d_in, const int* in_sizes, int n_in,
                              void* d_out, int out_size, void* d_ws, size_t ws_size,
                              hipStream_t stream)
{
    const float* z        = (const float*)d_in[0];
    const float* node_emb = (const float*)d_in[1];
    const int*   graph_id = (const int*)  d_in[2];
    const int*   src      = (const int*)  d_in[3];
    const int*   dst      = (const int*)  d_in[4];
    const float* lp_w  = (const float*)d_in[5];
    const float* lp_b  = (const float*)d_in[6];
    const float* nep_w = (const float*)d_in[7];
    const float* nep_b = (const float*)d_in[8];
    const float* nd1_w = (const float*)d_in[9];
    const float* nd1_b = (const float*)d_in[10];
    const float* nd2_w = (const float*)d_in[11];
    const float* nd2_b = (const float*)d_in[12];
    const float* ed1_w = (const float*)d_in[13];
    const float* ed1_b = (const float*)d_in[14];
    const float* ed2_w = (const float*)d_in[15];
    const float* ed2_b = (const float*)d_in[16];
    const float* en1_w = (const float*)d_in[17];
    const float* en1_b = (const float*)d_in[18];
    const float* en2_w = (const float*)d_in[19];
    const float* en2_b = (const float*)d_in[20];
    const float* st1_w = (const float*)d_in[21];
    const float* st1_b = (const float*)d_in[22];
    const float* st2_w = (const float*)d_in[23];
    const float* st2_b = (const float*)d_in[24];

    float* out = (float*)d_out;
    float* out_node   = out + OUT_NODE_OFF;
    float* out_edge   = out + OUT_EDGE_OFF;
    float* out_energy = out + OUT_ENERGY_OFF;
    float* out_stress = out + OUT_STRESS_OFF;

    float* ws     = (float*)d_ws;
    float* z_proj = ws + WS_ZPROJ;
    float* zc     = ws + WS_ZC;
    float* P1     = ws + WS_P1;
    float* P2     = ws + WS_P2;
    float4* T4    = (float4*)(ws + WS_T4);
    _Float16* w1s = (_Float16*)(ws + WS_W1T);
    _Float16* w2s = (_Float16*)(ws + WS_W2T);

    precompute_kernel<<<NB + 64, 256, 0, stream>>>(
        z, lp_w, lp_b, nd1_w, ed1_w,
        en1_w, en1_b, en2_w, en2_b, st1_w, st1_b, st2_w, st2_b, nep_w,
        z_proj, zc, P1, P2, w1s, w2s, out_energy, out_stress);

    edge_table_kernel<<<NB, NB, 0, stream>>>(P1, P2, ed1_b, ed2_w, ed2_b, T4);

    node_edge_kernel<<<NODE_BLK + EDGE_BLK, 512, 0, stream>>>(
        node_emb, graph_id, w1s, nep_b, w2s, nd1_b, nd2_w, nd2_b, zc,
        src, dst, T4, out_node, out_edge);
}